// Round 2
// baseline (1105.747 us; speedup 1.0000x reference)
//
#include <hip/hip_runtime.h>

// Problem: bs=8, seq=16, hw=32*32=1024, ck=256, cv=3, steps=seq-1=15
// R7 design: factor the recurrence. softmax(k_{i+1} k_i^T) and
// softmax(k_{i+1} m_k_i^T) depend only on k / m_k (precomputable) -> compute
// ALL attention matrices in one massively-parallel pass (p_all, fp16 P-tilde +
// per-wave-chunk softmax corrections C), leaving only the tiny linear combine
// (absorb: rec = 0.9 S pv + 0.1 T mv, MFMA with hi/lo-split fp32-exact V) on
// the serial path. Two passes of <=8 steps keep P (256MB) inside the 512MiB ws.
#define BS 8
#define SEQ 16
#define HW 1024
#define CK 256
#define CV 3
#define STEPS 15

#define SKP 264   // padded fp16 LDS row stride (256+8)
#define VTP 1032  // padded fp16 Vt row stride (1024+8)

typedef unsigned short u16;
typedef _Float16 half8 __attribute__((ext_vector_type(8)));  // MFMA A/B frag
typedef float floatx4 __attribute__((ext_vector_type(4)));   // MFMA C/D frag

__device__ __forceinline__ u16 f2h(float f) {
  _Float16 h = (_Float16)f;
  return __builtin_bit_cast(unsigned short, h);
}
__device__ __forceinline__ float h2f(u16 u) {
  _Float16 h = __builtin_bit_cast(_Float16, u);
  return (float)h;
}

// ---- scan_state (once, fully parallel): kh_all = fp16(k[:, i]) for all i,
//      m_kh_all[i] = m_k EMA (fp16 state, fp32 math), pv0 = v[:,0], m_v0 = 0,
//      gt = v[:,1:].  ILP-2: each thread runs TWO independent chunk chains. ----
__global__ __launch_bounds__(256) void scan_state(
    const float* __restrict__ k, const float* __restrict__ v,
    const float* __restrict__ att,
    u16* __restrict__ kh_all, u16* __restrict__ m_kh_all,
    float* __restrict__ pv0, float* __restrict__ mv0,
    float* __restrict__ out)
{
  long idx = (long)blockIdx.x * 256 + threadIdx.x;
  long stride = (long)gridDim.x * 256;
  const long NC2 = (long)BS * HW * 32 / 2;     // 131,072 chunk-pairs
  const long SSTR = (long)HW * CK;             // per-step element stride
  for (long t = idx; t < NC2; t += stride) {
    long ta = t, tb = t + NC2;
    long ba = ta >> 15, raa = ta & 32767, pa = raa >> 5, sa = raa & 31;
    long bb = tb >> 15, rab = tb & 32767, pb = rab >> 5, sb = rab & 31;
    const float* kpa = k + ((long)ba * SEQ * HW + pa) * CK + sa * 8;
    const float* kpb = k + ((long)bb * SEQ * HW + pb) * CK + sb * 8;
    u16* khpa = kh_all + ((long)ba * SEQ * HW + pa) * CK + sa * 8;
    u16* khpb = kh_all + ((long)bb * SEQ * HW + pb) * CK + sb * 8;
    u16* mkpa = m_kh_all + ((long)ba * STEPS * HW + pa) * CK + sa * 8;
    u16* mkpb = m_kh_all + ((long)bb * STEPS * HW + pb) * CK + sb * 8;
    const float* apa = att + (long)ba * SEQ * HW + pa;
    const float* apb = att + (long)bb * SEQ * HW + pb;
    u16 mha[8], mhb[8];
    #pragma unroll
    for (int j = 0; j < 8; ++j) { mha[j] = 0; mhb[j] = 0; }
    for (int i = 0; i < SEQ; ++i) {
      float4 a0 = *(const float4*)(kpa + (long)i * SSTR);
      float4 b0 = *(const float4*)(kpb + (long)i * SSTR);
      float4 a1 = *(const float4*)(kpa + (long)i * SSTR + 4);
      float4 b1 = *(const float4*)(kpb + (long)i * SSTR + 4);
      float kfa[8] = {a0.x, a0.y, a0.z, a0.w, a1.x, a1.y, a1.z, a1.w};
      float kfb[8] = {b0.x, b0.y, b0.z, b0.w, b1.x, b1.y, b1.z, b1.w};
      u16 ha[8], hb[8];
      #pragma unroll
      for (int j = 0; j < 8; ++j) { ha[j] = f2h(kfa[j]); hb[j] = f2h(kfb[j]); }
      *(int4*)(khpa + (long)i * SSTR) = *(const int4*)ha;
      *(int4*)(khpb + (long)i * SSTR) = *(const int4*)hb;
      if (i < STEPS) {
        float aa = apa[(long)i * HW], ab = apb[(long)i * HW];
        float ga = 1.0f / (1.0f + __expf(-aa)), oga = 1.0f - ga;
        float gb = 1.0f / (1.0f + __expf(-ab)), ogb = 1.0f - gb;
        #pragma unroll
        for (int j = 0; j < 8; ++j) {
          mha[j] = f2h(fmaf(ga, kfa[j], oga * h2f(mha[j])));
          mhb[j] = f2h(fmaf(gb, kfb[j], ogb * h2f(mhb[j])));
        }
        *(int4*)(mkpa + (long)i * SSTR) = *(const int4*)mha;
        *(int4*)(mkpb + (long)i * SSTR) = *(const int4*)mhb;
      }
    }
  }
  // pv0 = v[:,0], m_v0 = 0
  const long NV = (long)BS * HW * CV;
  for (long t = idx; t < NV; t += stride) {
    long b = t / (HW * CV), r = t - b * (HW * CV);
    pv0[t] = v[(long)b * SEQ * HW * CV + r];
    mv0[t] = 0.0f;
  }
  // gt = v[:,1:]
  const long NG = (long)BS * STEPS * HW * CV;
  for (long t = idx; t < NG; t += stride) {
    long b = t / (STEPS * HW * CV), r = t - b * (STEPS * HW * CV);
    long i = r / (HW * CV), rr = r - i * (HW * CV);
    out[NG + t] = v[((long)b * SEQ + i + 1) * (HW * CV) + rr];
  }
}

// --------- p_all: ALL attention matrices for a pass, fully parallel ---------
// grid ps*256 blocks, 512 thr = 8 waves. Decode co-locates the 32 q-tile
// blocks of one (b, step) group on one XCD (round-robin id%8 -> b = id&7).
// Per wave w (p-range [w*128,(w+1)*128)): scores held in regs (64/lane/mat),
// wave-level max/sum, store P~ = exp(s - M_w) fp16 to global, publish (M_w,l_w)
// to LDS; block-level merge writes C[q][w] = exp(M_w - M)/L.
__global__ __launch_bounds__(512, 2) void p_all(
    const u16* __restrict__ kh_all, const u16* __restrict__ m_kh_all,
    u16* __restrict__ P, float* __restrict__ C, int s0)
{
  __shared__ u16 Kq[32 * SKP];          // q-tile fp16 (16.9 KB)
  __shared__ float Mg[8][2][32][2];     // per-wave (M, l) per q (4 KB)

  const int id = blockIdx.x;
  const int b = id & 7;                 // batch == XCD (round-robin %8)
  const int j = (id >> 3) & 31;         // q-tile
  const int ls = id >> 8;               // pass-local step
  const int step = s0 + ls;
  const int g = ls * 8 + b;             // group index into P/C
  const int q0 = j * 32;
  const int tid = threadIdx.x;
  const int w = tid >> 6, lane = tid & 63;
  const int r = lane & 15, rg = lane >> 4;

  const u16* Kn = kh_all + (long)(b * SEQ + step + 1) * HW * CK;  // q side
  const u16* Kc = kh_all + (long)(b * SEQ + step) * HW * CK;      // p side
  const u16* Mb = m_kh_all + (long)(b * STEPS + step) * HW * CK;  // p side

  { // stage q-tile: 1024 16B-chunks over 512 threads
    #pragma unroll
    for (int jj = 0; jj < 2; ++jj) {
      int c = tid + jj * 512;
      int row = c >> 5, off = (c & 31) * 8;
      *(int4*)&Kq[row * SKP + off] = *(const int4*)(Kn + (long)(q0 + row) * CK + off);
    }
  }
  __syncthreads();

  half8 Bq[2][8];
  #pragma unroll
  for (int qi = 0; qi < 2; ++qi)
    #pragma unroll
    for (int kk = 0; kk < 8; ++kk)
      Bq[qi][kk] = *(const half8*)&Kq[(qi * 16 + r) * SKP + kk * 32 + rg * 8];

  #pragma unroll
  for (int mat = 0; mat < 2; ++mat) {
    const u16* Ab = mat ? Mb : Kc;
    floatx4 S[2][8];
    #pragma unroll
    for (int pc = 0; pc < 4; ++pc)
      #pragma unroll
      for (int pi = 0; pi < 2; ++pi) {
        const int pr = w * 128 + pc * 32 + pi * 16;
        half8 A[8];
        #pragma unroll
        for (int kk = 0; kk < 8; ++kk)
          A[kk] = *(const half8*)(Ab + (long)(pr + r) * CK + kk * 32 + rg * 8);
        floatx4 c0 = {0.f, 0.f, 0.f, 0.f}, c1 = {0.f, 0.f, 0.f, 0.f};
        #pragma unroll
        for (int kk = 0; kk < 8; ++kk) {
          c0 = __builtin_amdgcn_mfma_f32_16x16x32_f16(A[kk], Bq[0][kk], c0, 0, 0, 0);
          c1 = __builtin_amdgcn_mfma_f32_16x16x32_f16(A[kk], Bq[1][kk], c1, 0, 0, 0);
        }
        S[0][pc * 2 + pi] = c0;
        S[1][pc * 2 + pi] = c1;
      }
    #pragma unroll
    for (int qi = 0; qi < 2; ++qi) {
      float m = -1e30f;
      #pragma unroll
      for (int idx = 0; idx < 8; ++idx)
        #pragma unroll
        for (int jj = 0; jj < 4; ++jj)
          m = fmaxf(m, S[qi][idx][jj]);
      m = fmaxf(m, __shfl_xor(m, 16));
      m = fmaxf(m, __shfl_xor(m, 32));
      float l = 0.f;
      #pragma unroll
      for (int idx = 0; idx < 8; ++idx)
        #pragma unroll
        for (int jj = 0; jj < 4; ++jj) {
          float e = __expf(S[qi][idx][jj] - m);
          S[qi][idx][jj] = e;
          l += e;
        }
      l += __shfl_xor(l, 16);
      l += __shfl_xor(l, 32);
      if (rg == 0) { Mg[w][mat][qi * 16 + r][0] = m; Mg[w][mat][qi * 16 + r][1] = l; }
      // store P~ rows (fp16, [q][p] row-major)
      u16* Pr = P + ((long)(g * 2 + mat) * HW + q0 + qi * 16 + r) * HW;
      #pragma unroll
      for (int idx = 0; idx < 8; ++idx) {
        int pc = idx >> 1, pi = idx & 1;
        int p = w * 128 + pc * 32 + pi * 16 + rg * 4;
        u16 t4[4] = {f2h(S[qi][idx][0]), f2h(S[qi][idx][1]),
                     f2h(S[qi][idx][2]), f2h(S[qi][idx][3])};
        *(int2*)&Pr[p] = *(const int2*)t4;
      }
    }
  }
  __syncthreads();
  if (tid < 64) {  // block-level softmax merge -> corrections C[q][w]
    int mat = tid >> 5, q = tid & 31;
    float M = -1e30f;
    #pragma unroll
    for (int w8 = 0; w8 < 8; ++w8) M = fmaxf(M, Mg[w8][mat][q][0]);
    float L = 0.f;
    #pragma unroll
    for (int w8 = 0; w8 < 8; ++w8)
      L += Mg[w8][mat][q][1] * __expf(Mg[w8][mat][q][0] - M);
    float iL = 1.0f / L;
    float* Cg = C + ((long)g * 2 + mat) * HW * 8 + (long)(q0 + q) * 8;
    #pragma unroll
    for (int w8 = 0; w8 < 8; ++w8)
      Cg[w8] = __expf(Mg[w8][mat][q][0] - M) * iL;
  }
}

// --------- absorb (the only serial kernel, 15x): rec = 0.9 S pv + 0.1 T mv ---
// grid (8, 32), 256 thr = 4 waves = (mat, qsub). MFMA: A = V^T in LDS as
// hi/lo fp16 split (fp32-exact), B = P~ rows streamed from global.
// D[c][q]: col=lane&15 -> q, rows=(lane>>4)*4+reg -> c (real c=0..2 in rg=0).
// Fused m_v EMA (published by blockIdx.y==0); per-128p-chunk correction C.
__global__ __launch_bounds__(256) void absorb(
    const u16* __restrict__ P, const float* __restrict__ C,
    const float* __restrict__ v, const int* __restrict__ seq_mask,
    const float* __restrict__ att,
    const float* __restrict__ mv_in, float* __restrict__ mv_out,
    const float* __restrict__ pv_in, float* __restrict__ pv_out,
    float* __restrict__ out, int step, int g0)
{
  __shared__ __align__(16) u16 Vt[2][2][4][VTP];  // [mat][hi/lo][c-row(4)][p] 33 KB
  __shared__ float Cs[2][32][8];                  // corrections (2 KB)
  __shared__ float Acc[2][2][16][3];              // per-wave results (768 B)

  const int b = blockIdx.x, q0 = blockIdx.y * 32;
  const int tid = threadIdx.x;
  const int g = g0 + b;

  { // stage corrections
    const float* Cg = C + (long)g * 2 * HW * 8;
    for (int t2 = tid; t2 < 512; t2 += 256) {
      int mat = t2 >> 8, rest = t2 & 255, q = rest >> 3, w8 = rest & 7;
      Cs[mat][q][w8] = Cg[(long)mat * HW * 8 + (long)(q0 + q) * 8 + w8];
    }
  }
  { // stage V^T (hi/lo split) + fused m_v EMA + publish
    const float* ar = att + (long)(b * SEQ + step) * HW;
    #pragma unroll
    for (int pp = 0; pp < 4; ++pp) {
      int p = tid * 4 + pp;
      float a = ar[p];
      float gg = 1.0f / (1.0f + __expf(-a));
      float og = 1.0f - gg;
      long base = ((long)b * HW + p) * CV;
      #pragma unroll
      for (int c = 0; c < CV; ++c) {
        float pv = pv_in[base + c];
        float mv = fmaf(gg, pv, og * mv_in[base + c]);
        if (blockIdx.y == 0) mv_out[base + c] = mv;
        u16 sh = f2h(pv); u16 sl = f2h(pv - h2f(sh));
        u16 mh = f2h(mv); u16 ml = f2h(mv - h2f(mh));
        Vt[0][0][c][p] = sh; Vt[0][1][c][p] = sl;
        Vt[1][0][c][p] = mh; Vt[1][1][c][p] = ml;
      }
      // zero the clamp row (r>=3 lanes read row 3)
      Vt[0][0][3][p] = 0; Vt[0][1][3][p] = 0;
      Vt[1][0][3][p] = 0; Vt[1][1][3][p] = 0;
    }
  }
  __syncthreads();

  const int w4 = tid >> 6, lane = tid & 63, r = lane & 15, rg = lane >> 4;
  const int qsub = w4 & 1, mat = w4 >> 1;
  const int rc = r < 3 ? r : 3;
  const u16* Pr = P + ((long)(g * 2 + mat) * HW + q0 + qsub * 16 + r) * HW;

  floatx4 acc = {0.f, 0.f, 0.f, 0.f};
  #pragma unroll
  for (int wg = 0; wg < 8; ++wg) {
    floatx4 D = {0.f, 0.f, 0.f, 0.f};
    #pragma unroll
    for (int ch = 0; ch < 4; ++ch) {
      int p0 = wg * 128 + ch * 32 + rg * 8;
      half8 Bf  = *(const half8*)(Pr + p0);
      half8 Ahi = *(const half8*)&Vt[mat][0][rc][p0];
      half8 Alo = *(const half8*)&Vt[mat][1][rc][p0];
      D = __builtin_amdgcn_mfma_f32_16x16x32_f16(Ahi, Bf, D, 0, 0, 0);
      D = __builtin_amdgcn_mfma_f32_16x16x32_f16(Alo, Bf, D, 0, 0, 0);
    }
    float Cv = Cs[mat][qsub * 16 + r][wg];
    acc[0] = fmaf(Cv, D[0], acc[0]);
    acc[1] = fmaf(Cv, D[1], acc[1]);
    acc[2] = fmaf(Cv, D[2], acc[2]);
    acc[3] = fmaf(Cv, D[3], acc[3]);
  }
  if (rg == 0) {  // rows 0..2 = c, col = r = q-sub-index
    Acc[mat][qsub][r][0] = acc[0];
    Acc[mat][qsub][r][1] = acc[1];
    Acc[mat][qsub][r][2] = acc[2];
  }
  __syncthreads();

  if (tid < 128) {
    int q = tid >> 2, c = tid & 3;
    if (c < CV) {
      float rec = 0.9f * Acc[0][q >> 4][q & 15][c] + 0.1f * Acc[1][q >> 4][q & 15][c];
      const int maskv = seq_mask[b * SEQ + step];
      const int qg = q0 + q;
      out[((long)(b * STEPS + step) * HW + qg) * CV + c] = rec;
      const float vr = v[((long)(b * SEQ + step) * HW + qg) * CV + c];
      pv_out[((long)(b * HW + qg)) * CV + c] = maskv ? vr : rec;
    }
  }
}

extern "C" void kernel_launch(void* const* d_in, const int* in_sizes, int n_in,
                              void* d_out, int out_size, void* d_ws, size_t ws_size,
                              hipStream_t stream) {
  const float* k   = (const float*)d_in[0];
  const float* v   = (const float*)d_in[1];
  const float* att = (const float*)d_in[2];
  const int* seq_mask = (const int*)d_in[3];
  float* out = (float*)d_out;
  char* ws = (char*)d_ws;

  const size_t KH_ALL  = (size_t)BS * SEQ * HW * CK * 2;    //  67,108,864
  const size_t MKH_ALL = (size_t)BS * STEPS * HW * CK * 2;  //  62,914,560
  const size_t SV      = (size_t)BS * HW * CV * 4;          //      98,304
  const size_t PSTEP_P = (size_t)BS * 2 * HW * HW * 2;      //  33,554,432
  const size_t PSTEP_C = (size_t)BS * 2 * HW * 8 * 4;       //     524,288
  const size_t FIXED   = KH_ALL + MKH_ALL + 4 * SV;         // 130,416,640

  int ps_max = (ws_size > FIXED) ? (int)((ws_size - FIXED) / (PSTEP_P + PSTEP_C)) : 1;
  if (ps_max < 1) ps_max = 1;
  if (ps_max > STEPS) ps_max = STEPS;
  const int PASS = ps_max < 8 ? ps_max : 8;

  u16*   kh_all   = (u16*)(ws);
  u16*   m_kh_all = (u16*)(ws + KH_ALL);
  float* pvA      = (float*)(ws + KH_ALL + MKH_ALL);
  float* pvB      = (float*)(ws + KH_ALL + MKH_ALL + SV);
  float* mvA      = (float*)(ws + KH_ALL + MKH_ALL + 2 * SV);
  float* mvB      = (float*)(ws + KH_ALL + MKH_ALL + 3 * SV);
  float* Cbuf     = (float*)(ws + FIXED);
  u16*   Pbuf     = (u16*)(ws + FIXED + (size_t)PASS * PSTEP_C);

  // all conversions + m_k EMA scan + pv0/mv0 init + gt copy (parallel)
  scan_state<<<512, 256, 0, stream>>>(k, v, att, kh_all, m_kh_all, pvA, mvA, out);

  for (int s0 = 0; s0 < STEPS; s0 += PASS) {
    int ps = (s0 + PASS <= STEPS) ? PASS : (STEPS - s0);
    // all GEMM+softmax work for this pass, fully parallel across steps
    p_all<<<ps * 256, 512, 0, stream>>>(kh_all, m_kh_all, Pbuf, Cbuf, s0);
    // serial linear combine
    for (int i = s0; i < s0 + ps; ++i) {
      int ls = i - s0;
      float* pin  = (i & 1) ? pvB : pvA;
      float* pout = (i & 1) ? pvA : pvB;
      float* mvi  = (i & 1) ? mvB : mvA;
      float* mvo  = (i & 1) ? mvA : mvB;
      absorb<<<dim3(BS, 32), 256, 0, stream>>>(Pbuf, Cbuf, v, seq_mask, att,
                                               mvi, mvo, pin, pout, out, i, ls * 8);
    }
  }
}